// Round 13
// baseline (178.328 us; speedup 1.0000x reference)
//
#include <hip/hip_runtime.h>
#include <hip/hip_bf16.h>
#include <math.h>

typedef __attribute__((ext_vector_type(4))) float f32x4;
typedef __attribute__((ext_vector_type(8))) short bf16x8;

#define N_ROWS 8192
#define D 256
#define MSHIFT 16.0f
#define NKB 8
#define KRANGE (N_ROWS / NKB)     // 1024
#define NSTEP (KRANGE / 64)       // 16 (BK=64)

__device__ __forceinline__ unsigned short f2bf(float f) {
    unsigned int u = __float_as_uint(f);
    unsigned int r = u + 0x7FFFu + ((u >> 16) & 1u);
    return (unsigned short)(r >> 16);
}
__device__ __forceinline__ float bf2f(unsigned short h) {
    return __uint_as_float(((unsigned int)h) << 16);
}

__device__ __forceinline__ float breduce_sum256(float v, float* sb) {
#pragma unroll
    for (int off = 32; off; off >>= 1) v += __shfl_down(v, off);
    int wid = threadIdx.x >> 6;
    __syncthreads();
    if ((threadIdx.x & 63) == 0) sb[wid] = v;
    __syncthreads();
    return sb[0] + sb[1] + sb[2] + sb[3];
}

__device__ __forceinline__ void dma16(const void* g, void* l) {
    __builtin_amdgcn_global_load_lds(
        (const __attribute__((address_space(1))) unsigned int*)g,
        (__attribute__((address_space(3))) unsigned int*)l, 16, 0, 0);
}

// expand 8 adjacency bits (starting at bit sh of w32) to bf16 0/1
__device__ __forceinline__ bf16x8 bits2bf(unsigned int w32, int sh) {
    unsigned int m = w32 >> sh;
    bf16x8 r;
#pragma unroll
    for (int j = 0; j < 8; ++j)
        r[j] = (m & (1u << j)) ? (short)0x3F80 : (short)0;
    return r;
}

// K0: coalesced adj -> 1-bit pack.  pack[i][w] bit b = adj[i][32w+b] != 0.
// 2048 blocks x 256 thr, 4 rows/block. Lane-adjacent int4 loads (dense 128B
// lines), LDS nibble assembly, 128B-contiguous word stores.
__global__ void k_pack(const int* __restrict__ adj, unsigned int* __restrict__ pack) {
    __shared__ unsigned int nib[256];
    const int row0 = blockIdx.x * 4;
    const int t = threadIdx.x;
#pragma unroll
    for (int r = 0; r < 4; ++r) {
        const int4* src = (const int4*)(adj + (size_t)(row0 + r) * N_ROWS);
#pragma unroll
        for (int it = 0; it < 8; ++it) {
            int4 a = src[it * 256 + t];
            unsigned int nb = (a.x ? 1u : 0u) | (a.y ? 2u : 0u) |
                              (a.z ? 4u : 0u) | (a.w ? 8u : 0u);
            __syncthreads();
            nib[t] = nb;
            __syncthreads();
            if (t < 32) {
                unsigned int wd = 0;
#pragma unroll
                for (int s = 0; s < 8; ++s) wd |= nib[t * 8 + s] << (4 * s);
                pack[(size_t)(row0 + r) * 256 + it * 32 + t] = wd;
            }
        }
    }
}

// K1: M2 row k (f32) -> M2T hi/lo bf16 split [j][k]; v[k] = sum_j M2[k][j]*a2[j]
__global__ void k_M2v(const float* __restrict__ Wg, const float* __restrict__ Wa,
                      const float* __restrict__ aatt,
                      unsigned short* __restrict__ M2Thi, unsigned short* __restrict__ M2Tlo,
                      float* __restrict__ v) {
    __shared__ float sb[4];
    int k = blockIdx.x, t = threadIdx.x;
    float acc = 0.f;
#pragma unroll 8
    for (int m = 0; m < 255; ++m)
        acc += Wg[k * 255 + m] * Wa[(m + 1) * 256 + t];
    unsigned short hi = f2bf(acc);
    unsigned short lo = f2bf(acc - bf2f(hi));
    M2Thi[t * 256 + k] = hi;
    M2Tlo[t * 256 + k] = lo;
    if (k == 0) { M2Thi[t * 256 + 255] = 0; M2Tlo[t * 256 + 255] = 0; }
    float s = breduce_sum256(acc * aatt[256 + t], sb);
    if (t == 0) v[k] = s;
}

// K2: per-row logmap0 + c = logx.v + wexp; write wbf and w-scaled logx hi/lo bf16 (k-shifted)
__global__ void k_logw(const float* __restrict__ x, const float* __restrict__ v,
                       unsigned short* __restrict__ wbf,
                       unsigned short* __restrict__ Awhi, unsigned short* __restrict__ Awlo) {
    __shared__ float sb[4];
    int i0 = blockIdx.x * 8, t = threadIdx.x;
    float vv = (t >= 1) ? v[t - 1] : 0.f;
#pragma unroll
    for (int r = 0; r < 8; ++r) {
        float xv = x[(size_t)(i0 + r) * D + t];
        float yv = (t >= 1) ? xv : 0.f;
        float ss = breduce_sum256(yv * yv, sb);
        float x0 = x[(size_t)(i0 + r) * D];
        float coef = acoshf(fmaxf(x0, 1.f + 1e-7f)) / fmaxf(sqrtf(ss), 1e-15f);
        float lg = coef * yv;                 // logx[i][t]
        float c = breduce_sum256(lg * vv, sb);
        float w = expf(c - MSHIFT);
        if (t == r) wbf[i0 + r] = f2bf(w);
        float aw = w * lg;
        unsigned short hi = f2bf(aw);
        unsigned short lo = f2bf(aw - bf2f(hi));
        int kd = (t == 0) ? 255 : (t - 1);    // Aw[i][k] = w*logx[i][k+1], pad k=255 -> 0
        Awhi[(size_t)(i0 + r) * 256 + kd] = hi;
        Awlo[(size_t)(i0 + r) * 256 + kd] = lo;
    }
}

// K3: GT[c][i] = sum_k M2T[c][k] * Aw[i][k]  (3-term hi/lo MFMA). 512 thr, 64 i-cols/block.
__global__ void __launch_bounds__(512)
k_hGT(const unsigned short* __restrict__ M2Thi, const unsigned short* __restrict__ M2Tlo,
      const unsigned short* __restrict__ Awhi, const unsigned short* __restrict__ Awlo,
      unsigned short* __restrict__ GT) {
    __shared__ __align__(16) char ahi[32768], alo[32768], bhi[8192], blo[8192];
    const int tid = threadIdx.x;
    const int w = tid >> 6, l = tid & 63;
    const int lr = l & 15, lq = l >> 4;
    const int i0 = blockIdx.x * 64;
    const int gs = (l & 7) ^ (l >> 3);

    const unsigned short* srcAhi[4];
    const unsigned short* srcAlo[4];
#pragma unroll
    for (int i = 0; i < 4; ++i) {
        int rowA = (w * 4 + i) * 8 + (l >> 3);
        srcAhi[i] = M2Thi + rowA * 256 + gs * 8;
        srcAlo[i] = M2Tlo + rowA * 256 + gs * 8;
    }
    int rowB = w * 8 + (l >> 3);
    const unsigned short* srcBhi = Awhi + (size_t)(i0 + rowB) * 256 + gs * 8;
    const unsigned short* srcBlo = Awlo + (size_t)(i0 + rowB) * 256 + gs * 8;

    f32x4 zero4 = {0.f, 0.f, 0.f, 0.f};
    f32x4 acc[2][4];
#pragma unroll
    for (int m = 0; m < 2; ++m)
#pragma unroll
        for (int n = 0; n < 4; ++n) acc[m][n] = zero4;

    for (int t = 0; t < 4; ++t) {
        if (t) __syncthreads();
#pragma unroll
        for (int i = 0; i < 4; ++i) {
            dma16(srcAhi[i] + t * 64, ahi + (w * 4 + i) * 1024);
            dma16(srcAlo[i] + t * 64, alo + (w * 4 + i) * 1024);
        }
        dma16(srcBhi + t * 64, bhi + w * 1024);
        dma16(srcBlo + t * 64, blo + w * 1024);
        asm volatile("s_waitcnt vmcnt(0)" ::: "memory");
        __syncthreads();
#pragma unroll
        for (int ks = 0; ks < 2; ++ks) {
            const int g = ((ks * 4 + lq) ^ (lr & 7)) * 16;
            bf16x8 afh[2], afl[2];
#pragma unroll
            for (int m = 0; m < 2; ++m) {
                int row = w * 32 + m * 16 + lr;
                afh[m] = *(const bf16x8*)(ahi + row * 128 + g);
                afl[m] = *(const bf16x8*)(alo + row * 128 + g);
            }
#pragma unroll
            for (int n = 0; n < 4; ++n) {
                int rb = n * 16 + lr;
                bf16x8 bfh = *(const bf16x8*)(bhi + rb * 128 + g);
                bf16x8 bfl = *(const bf16x8*)(blo + rb * 128 + g);
#pragma unroll
                for (int m = 0; m < 2; ++m) {
                    acc[m][n] = __builtin_amdgcn_mfma_f32_16x16x32_bf16(afh[m], bfh, acc[m][n], 0, 0, 0);
                    acc[m][n] = __builtin_amdgcn_mfma_f32_16x16x32_bf16(afh[m], bfl, acc[m][n], 0, 0, 0);
                    acc[m][n] = __builtin_amdgcn_mfma_f32_16x16x32_bf16(afl[m], bfh, acc[m][n], 0, 0, 0);
                }
            }
        }
    }
#pragma unroll
    for (int m = 0; m < 2; ++m)
#pragma unroll
        for (int n = 0; n < 4; ++n)
#pragma unroll
            for (int vv = 0; vv < 4; ++vv) {
                int c = w * 32 + m * 16 + lq * 4 + vv;
                GT[(size_t)c * N_ROWS + i0 + n * 16 + lr] = f2bf(acc[m][n][vv]);
            }
}

// K4: masked GEMM from bit-mask. BM=256, BN=256, BK=64. 512 thr (8 waves, 4m x 2n).
// A: the block's ENTIRE 256-row x 1024-k bit slice (32 KB) staged once into
// padded LDS at prologue -> zero per-step A staging. B (GT, XCD-pinned L2 slice)
// triple-buffered dma16: wait vmcnt(4) -> barrier -> stage(t+2) -> compute(t).
__global__ void __launch_bounds__(512, 2)
k_attbits(const unsigned int* __restrict__ pack, const unsigned short* __restrict__ GT,
          const unsigned short* __restrict__ wbf, float* __restrict__ part,
          float* __restrict__ rspart) {
    __shared__ __align__(16) unsigned int bitlds[256 * 36];  // pad 36 -> conflict-free
    __shared__ __align__(16) char bufB[3][32768];            // 256 cols x 64 bf16
    __shared__ __align__(16) char wlds[2048];                // KRANGE bf16 weights
    const int tid = threadIdx.x;
    const int kb = blockIdx.x & 7;         // XCD-pinned GT k-slice
    const int rb = blockIdx.x >> 3;        // 0..31
    const int i0 = rb * 256;
    const int kbeg = kb * KRANGE;
    const int kw0 = kbeg >> 5;             // word offset in pack row
    const int w = tid >> 6, l = tid & 63;
    const int lr = l & 15, lq = l >> 4;
    const int wm = w >> 1, wn = w & 1;     // 4 row-groups x 2 col-groups

    // ---- bits prologue: coalesced reg-stage (8 lanes x 16B per row)
    {
        const int rloc = tid >> 3, gb = tid & 7;
        uint4 vbits[4];
#pragma unroll
        for (int p = 0; p < 4; ++p)
            vbits[p] = *(const uint4*)(pack + (size_t)(i0 + p * 64 + rloc) * 256 + kw0 + gb * 4);
#pragma unroll
        for (int p = 0; p < 4; ++p)
            *(uint4*)(bitlds + (p * 64 + rloc) * 36 + gb * 4) = vbits[p];
    }

    // ---- B dma sources (pre-swizzled granule: LDS[col][g] = glob[col][g^(col&7)])
    const unsigned short* srcB[4];
#pragma unroll
    for (int i = 0; i < 4; ++i) {
        int b = w * 4 + i;
        int col = b * 8 + (l >> 3);
        srcB[i] = GT + (size_t)col * N_ROWS + kbeg + ((l & 7) ^ ((l >> 3) & 7)) * 8;
    }
#define STAGEB(T_, BI_) do {                                           \
        char* dstB = bufB[BI_];                                        \
        _Pragma("unroll")                                              \
        for (int i_ = 0; i_ < 4; ++i_)                                 \
            dma16(srcB[i_] + (T_) * 64, dstB + (w * 4 + i_) * 1024);   \
    } while (0)

    f32x4 zero4 = {0.f, 0.f, 0.f, 0.f};
    f32x4 acc[4][8], acc_rs[4];
#pragma unroll
    for (int m = 0; m < 4; ++m) {
        acc_rs[m] = zero4;
#pragma unroll
        for (int n = 0; n < 8; ++n) acc[m][n] = zero4;
    }

    // prologue staging: B(0), B(1), weights; drain all + publish bits
    STAGEB(0, 0);
    STAGEB(1, 1);
    if (w < 2) dma16(wbf + kbeg + w * 512 + l * 8, wlds + w * 1024);
    __syncthreads();

    int cb = 0;
    for (int t = 0; t < NSTEP; ++t) {
        if (t > 0) {
            if (t < NSTEP - 1) asm volatile("s_waitcnt vmcnt(4)" ::: "memory");
            else               asm volatile("s_waitcnt vmcnt(0)" ::: "memory");
            __builtin_amdgcn_sched_barrier(0);
            __builtin_amdgcn_s_barrier();
            __builtin_amdgcn_sched_barrier(0);
        }
        if (t + 2 < NSTEP) {
            int nb2 = (cb >= 1) ? cb - 1 : cb + 2;   // (t+2)%3
            STAGEB(t + 2, nb2);
        }
        const char* bB = bufB[cb];

        bf16x8 wf0 = {0, 0, 0, 0, 0, 0, 0, 0}, wf1 = wf0;
        if (lr == 0) {
            wf0 = *(const bf16x8*)(wlds + t * 128 + lq * 16);
            wf1 = *(const bf16x8*)(wlds + t * 128 + 64 + lq * 16);
        }
#pragma unroll
        for (int ks = 0; ks < 2; ++ks) {
            bf16x8 af[4];
#pragma unroll
            for (int m = 0; m < 4; ++m) {
                int row = wm * 64 + m * 16 + lr;
                unsigned int bits = bitlds[row * 36 + 2 * t + ks];
                af[m] = bits2bf(bits, lq * 8);
                acc_rs[m] = __builtin_amdgcn_mfma_f32_16x16x32_bf16(
                    af[m], ks ? wf1 : wf0, acc_rs[m], 0, 0, 0);
            }
#pragma unroll
            for (int n = 0; n < 8; ++n) {
                int col = wn * 128 + n * 16 + lr;
                bf16x8 bf = *(const bf16x8*)(bB + col * 128 + (((ks * 4 + lq) ^ (lr & 7))) * 16);
#pragma unroll
                for (int m = 0; m < 4; ++m)
                    acc[m][n] = __builtin_amdgcn_mfma_f32_16x16x32_bf16(af[m], bf, acc[m][n], 0, 0, 0);
            }
        }
        cb = (cb == 2) ? 0 : cb + 1;
    }
#undef STAGEB

    // rowsum (col 0 of acc_rs; wn duplicates -> wn==0 writes)
    if (wn == 0 && lr == 0) {
#pragma unroll
        for (int m = 0; m < 4; ++m)
#pragma unroll
            for (int vv = 0; vv < 4; ++vv)
                rspart[(size_t)kb * N_ROWS + i0 + wm * 64 + m * 16 + lq * 4 + vv] = acc_rs[m][vv];
    }

    // C write (layout: col=lane&15, row=(lane>>4)*4+reg); nontemporal
    float* pbase = part + (size_t)kb * N_ROWS * D;
#pragma unroll
    for (int m = 0; m < 4; ++m)
#pragma unroll
        for (int n = 0; n < 8; ++n) {
            int orow = i0 + wm * 64 + m * 16 + lq * 4;
            int ocol = wn * 128 + n * 16 + lr;
            float* op = pbase + (size_t)orow * D + ocol;
#pragma unroll
            for (int vv = 0; vv < 4; ++vv)
                __builtin_nontemporal_store(acc[m][n][vv], op + (size_t)vv * D);
        }
}

// K5: split-K reduce + epilogue (divide, elu, proj, logmap0, sigmoid, expmap0)
__global__ void k_final3(const float* __restrict__ part, const float* __restrict__ rspart,
                         float* __restrict__ out) {
    __shared__ float sb[4];
    int row = blockIdx.x, t = threadIdx.x;
    float raw = 0.f, rs = 0.f;
#pragma unroll
    for (int kbi = 0; kbi < NKB; ++kbi) {
        raw += __builtin_nontemporal_load(&part[((size_t)kbi * N_ROWS + row) * D + t]);
        rs += rspart[(size_t)kbi * N_ROWS + row];
    }
    float hp = raw / rs;
    float ey = 0.f;
    if (t >= 1) ey = (hp > 0.f) ? hp : expm1f(hp);
    float ss = breduce_sum256(ey * ey, sb);
    float x0 = sqrtf(1.f + ss);
    float th = fmaxf(x0, 1.f + 1e-7f);
    float al = acoshf(th);
    float yn = fmaxf(sqrtf(ss), 1e-15f);
    float u = (t >= 1) ? (al * ey / yn) : 0.f;
    float s = 1.f / (1.f + expf(-u));
    float s2 = (t >= 1) ? s * s : 0.f;
    float ssn = breduce_sum256(s2, sb);
    float xn = fmaxf(sqrtf(ssn), 1e-15f);
    float sh = sinhf(xn);
    float yf = (t >= 1) ? (sh * s / xn) : 0.f;
    float sy = breduce_sum256(yf * yf, sb);
    float res = (t == 0) ? sqrtf(1.f + sy) : yf;
    out[(size_t)row * D + t] = res;
}

extern "C" void kernel_launch(void* const* d_in, const int* in_sizes, int n_in,
                              void* d_out, int out_size, void* d_ws, size_t ws_size,
                              hipStream_t stream) {
    const float* x    = (const float*)d_in[0];
    const int*   adj  = (const int*)d_in[1];
    const float* Wg   = (const float*)d_in[3];
    const float* Wa   = (const float*)d_in[4];
    const float* aatt = (const float*)d_in[5];
    float* out = (float*)d_out;

    char* wsb = (char*)d_ws;
    unsigned short* M2Thi  = (unsigned short*)(wsb);              // 128 KB
    unsigned short* M2Tlo  = (unsigned short*)(wsb + 0x0020000);  // 128 KB
    float*          v      = (float*)(wsb + 0x0040000);           // 1 KB
    unsigned short* wbf    = (unsigned short*)(wsb + 0x0048000);  // 16 KB
    unsigned short* Awhi   = (unsigned short*)(wsb + 0x0100000);  // 4 MB
    unsigned short* Awlo   = (unsigned short*)(wsb + 0x0500000);  // 4 MB
    unsigned short* GT     = (unsigned short*)(wsb + 0x0900000);  // 4 MB
    float*          rspart = (float*)(wsb + 0x0D00000);           // 256 KB
    float*          part   = (float*)(wsb + 0x1000000);           // 64 MB (NKB x 8 MB)
    unsigned int*   pack   = (unsigned int*)(wsb + 0x5000000);    // 8 MB

    k_pack<<<N_ROWS / 4, 256, 0, stream>>>(adj, pack);
    k_M2v<<<255, 256, 0, stream>>>(Wg, Wa, aatt, M2Thi, M2Tlo, v);
    k_logw<<<N_ROWS / 8, 256, 0, stream>>>(x, v, wbf, Awhi, Awlo);
    k_hGT<<<N_ROWS / 64, 512, 0, stream>>>(M2Thi, M2Tlo, Awhi, Awlo, GT);
    k_attbits<<<32 * NKB, 512, 0, stream>>>(pack, GT, wbf, part, rspart);
    k_final3<<<N_ROWS, 256, 0, stream>>>(part, rspart, out);
}